// Round 1
// baseline (730.917 us; speedup 1.0000x reference)
//
#include <hip/hip_runtime.h>

#define NN 100000
#define NE 1280000
#define K_FEAT 500
#define K_TEXT 384
#define H 64

// ---------------- weight fusion: Wfx = w_feat @ w1_top, Wtx = w_text @ w1_bot,
// bpre = b_feat @ w1_top + b_text @ w1_bot ----------------
__global__ void fuse_k(const float* __restrict__ wf, const float* __restrict__ bf,
                       const float* __restrict__ wt, const float* __restrict__ bt,
                       const float* __restrict__ w1,
                       float* __restrict__ Wfx, float* __restrict__ Wtx,
                       float* __restrict__ bpre) {
    const int idx = blockIdx.x * 256 + threadIdx.x;
    const int TOT1 = K_FEAT * H;
    const int TOT2 = TOT1 + K_TEXT * H;
    if (idx < TOT1) {
        const int i = idx >> 6, j = idx & 63;
        float s = 0.f;
        #pragma unroll 8
        for (int t = 0; t < 64; ++t) s = fmaf(wf[i * 64 + t], w1[t * 64 + j], s);
        Wfx[idx] = s;
    } else if (idx < TOT2) {
        const int r = idx - TOT1;
        const int i = r >> 6, j = r & 63;
        float s = 0.f;
        #pragma unroll 8
        for (int t = 0; t < 64; ++t) s = fmaf(wt[i * 64 + t], w1[(64 + t) * 64 + j], s);
        Wtx[r] = s;
    } else if (idx < TOT2 + H) {
        const int j = idx - TOT2;
        float s = 0.f;
        for (int t = 0; t < 64; ++t) s = fmaf(bf[t], w1[t * 64 + j], s);
        for (int t = 0; t < 64; ++t) s = fmaf(bt[t], w1[(64 + t) * 64 + j], s);
        bpre[j] = s;
    }
}

// ---------------- degree / dinv ----------------
__global__ void deg_k(const int* __restrict__ ei, int* __restrict__ deg) {
    const int e = blockIdx.x * 256 + threadIdx.x;
    if (e < NE) atomicAdd(&deg[ei[NE + e]], 1);
}

__global__ void dinv_k(const int* __restrict__ deg, float* __restrict__ dinv) {
    const int i = blockIdx.x * 256 + threadIdx.x;
    if (i < NN) dinv[i] = rsqrtf((float)deg[i] + 1.0f);
}

// ---------------- GEMM1: u1[N,64] = (x@Wfx + txt@Wtx + bpre) * dinv[row] ----------------
__global__ __launch_bounds__(128)
void gemm1_k(const float* __restrict__ x, const float* __restrict__ txt,
             const float* __restrict__ Wfx, const float* __restrict__ Wtx,
             const float* __restrict__ bpre, const float* __restrict__ dinv,
             float* __restrict__ u1) {
    __shared__ float As[16][132];   // k-major, padded (132 = 33*4 keeps 16B align, breaks bank pattern)
    __shared__ float Bs[16][64];
    const int t = threadIdx.x;
    const int row0 = blockIdx.x * 128;
    const int ty = t >> 3;          // 0..15 -> rows ty*8..+7
    const int tx = t & 7;           // 0..7  -> cols tx*8..+7
    float acc[8][8];
    #pragma unroll
    for (int i = 0; i < 8; ++i)
        #pragma unroll
        for (int j = 0; j < 8; ++j) acc[i][j] = 0.f;

    auto run = [&](const float* __restrict__ A, const float* __restrict__ W, const int K) {
        const int ntile = (K + 15) >> 4;
        for (int kt = 0; kt < ntile; ++kt) {
            const int k0 = kt << 4;
            // stage A tile: 128 rows x 16 k (zero-filled at tails)
            #pragma unroll
            for (int i = 0; i < 4; ++i) {
                const int r = (t >> 2) + i * 32;
                const int kk4 = (t & 3) << 2;
                float4 v = make_float4(0.f, 0.f, 0.f, 0.f);
                const int row = row0 + r;
                if (row < NN && (k0 + kk4) < K)
                    v = *reinterpret_cast<const float4*>(&A[(long)row * K + k0 + kk4]);
                As[kk4 + 0][r] = v.x; As[kk4 + 1][r] = v.y;
                As[kk4 + 2][r] = v.z; As[kk4 + 3][r] = v.w;
            }
            // stage B tile: 16 k x 64 cols
            #pragma unroll
            for (int i = 0; i < 2; ++i) {
                const int kk = (t >> 4) + i * 8;
                const int c4 = (t & 15) << 2;
                float4 w = make_float4(0.f, 0.f, 0.f, 0.f);
                if (k0 + kk < K)
                    w = *reinterpret_cast<const float4*>(&W[(k0 + kk) * H + c4]);
                *reinterpret_cast<float4*>(&Bs[kk][c4]) = w;
            }
            __syncthreads();
            #pragma unroll
            for (int kk = 0; kk < 16; ++kk) {
                const float4 a0 = *reinterpret_cast<const float4*>(&As[kk][ty * 8]);
                const float4 a1 = *reinterpret_cast<const float4*>(&As[kk][ty * 8 + 4]);
                const float4 b0 = *reinterpret_cast<const float4*>(&Bs[kk][tx * 8]);
                const float4 b1 = *reinterpret_cast<const float4*>(&Bs[kk][tx * 8 + 4]);
                const float a[8] = {a0.x, a0.y, a0.z, a0.w, a1.x, a1.y, a1.z, a1.w};
                const float b[8] = {b0.x, b0.y, b0.z, b0.w, b1.x, b1.y, b1.z, b1.w};
                #pragma unroll
                for (int i = 0; i < 8; ++i)
                    #pragma unroll
                    for (int j = 0; j < 8; ++j)
                        acc[i][j] = fmaf(a[i], b[j], acc[i][j]);
            }
            __syncthreads();
        }
    };
    run(x, Wfx, K_FEAT);
    run(txt, Wtx, K_TEXT);

    #pragma unroll
    for (int i = 0; i < 8; ++i) {
        const int row = row0 + ty * 8 + i;
        if (row < NN) {
            const float di = dinv[row];
            #pragma unroll
            for (int j = 0; j < 8; ++j) {
                const int c = tx * 8 + j;
                u1[(long)row * H + c] = (acc[i][j] + bpre[c]) * di;
            }
        }
    }
}

// ---------------- scatter layer 1: agg1[dst] += u1[src], 64 ch, 4 edges per wave ----------------
__global__ __launch_bounds__(256)
void scat1_k(const int* __restrict__ ei, const float* __restrict__ u1,
             float* __restrict__ agg1) {
    const int lane = threadIdx.x & 63;
    const int wid = blockIdx.x * 4 + (threadIdx.x >> 6);
    const int e0 = wid * 4;
    #pragma unroll
    for (int i = 0; i < 4; ++i) {
        const int e = e0 + i;
        if (e < NE) {
            const int s = ei[e];
            const int d = ei[NE + e];
            const float v = u1[(long)s * H + lane];
            unsafeAtomicAdd(&agg1[(long)d * H + lane], v);
        }
    }
}

// ---------------- post layer1 + GEMM2: u2[N,8] = dinv * (relu(dinv*(agg1+u1)+b1) @ w2) ----------------
__global__ __launch_bounds__(256)
void post1_k(const float* __restrict__ agg1, const float* __restrict__ u1,
             const float* __restrict__ dinv, const float* __restrict__ b1,
             const float* __restrict__ w2, float* __restrict__ u2) {
    const int lane = threadIdx.x & 63;
    const int row = blockIdx.x * 4 + (threadIdx.x >> 6);
    if (row >= NN) return;
    const float di = dinv[row];
    float h = di * (agg1[(long)row * H + lane] + u1[(long)row * H + lane]) + b1[lane];
    h = fmaxf(h, 0.f);
    #pragma unroll
    for (int j = 0; j < 7; ++j) {
        float s = h * w2[lane * 7 + j];
        #pragma unroll
        for (int m = 1; m < 64; m <<= 1) s += __shfl_xor(s, m, 64);
        if (lane == j) u2[row * 8 + j] = di * s;
    }
}

// ---------------- scatter layer 2: agg2[dst] += u2[src], 7 ch ----------------
__global__ __launch_bounds__(256)
void scat2_k(const int* __restrict__ ei, const float* __restrict__ u2,
             float* __restrict__ agg2) {
    const int c = threadIdx.x & 7;
    const int g = blockIdx.x * 32 + (threadIdx.x >> 3);
    const int e0 = g * 4;
    #pragma unroll
    for (int i = 0; i < 4; ++i) {
        const int e = e0 + i;
        if (e < NE && c < 7) {
            const int s = ei[e];
            const int d = ei[NE + e];
            unsafeAtomicAdd(&agg2[d * 8 + c], u2[s * 8 + c]);
        }
    }
}

// ---------------- final: out = dinv*(agg2+u2) + b2 ----------------
__global__ void final_k(const float* __restrict__ agg2, const float* __restrict__ u2,
                        const float* __restrict__ dinv, const float* __restrict__ b2,
                        float* __restrict__ out) {
    const int idx = blockIdx.x * 256 + threadIdx.x;
    if (idx < NN * 7) {
        const int row = idx / 7;
        const int j = idx - row * 7;
        out[idx] = dinv[row] * (agg2[row * 8 + j] + u2[row * 8 + j]) + b2[j];
    }
}

extern "C" void kernel_launch(void* const* d_in, const int* in_sizes, int n_in,
                              void* d_out, int out_size, void* d_ws, size_t ws_size,
                              hipStream_t stream) {
    const float* x      = (const float*)d_in[0];
    const float* txt    = (const float*)d_in[1];
    const int*   ei     = (const int*)d_in[2];
    const float* w_feat = (const float*)d_in[3];
    const float* b_feat = (const float*)d_in[4];
    const float* w_text = (const float*)d_in[5];
    const float* b_text = (const float*)d_in[6];
    const float* w1     = (const float*)d_in[7];
    const float* b1     = (const float*)d_in[8];
    const float* w2     = (const float*)d_in[9];
    const float* b2     = (const float*)d_in[10];
    float* out = (float*)d_out;

    char* p = (char*)d_ws;
    auto alloc = [&](size_t bytes) {
        char* r = p;
        p += (bytes + 255) & ~(size_t)255;
        return r;
    };
    float* Wfx  = (float*)alloc((size_t)K_FEAT * H * 4);
    float* Wtx  = (float*)alloc((size_t)K_TEXT * H * 4);
    float* bpre = (float*)alloc(H * 4);
    int*   deg  = (int*)alloc((size_t)NN * 4);
    float* dinv = (float*)alloc((size_t)NN * 4);
    float* u1   = (float*)alloc((size_t)NN * H * 4);
    float* agg1 = (float*)alloc((size_t)NN * H * 4);
    float* u2   = (float*)alloc((size_t)NN * 8 * 4);
    float* agg2 = (float*)alloc((size_t)NN * 8 * 4);

    hipMemsetAsync(deg, 0, (size_t)NN * 4, stream);
    hipMemsetAsync(agg1, 0, (size_t)NN * H * 4, stream);
    hipMemsetAsync(agg2, 0, (size_t)NN * 8 * 4, stream);

    const int fuse_tot = K_FEAT * H + K_TEXT * H + H;
    fuse_k<<<(fuse_tot + 255) / 256, 256, 0, stream>>>(w_feat, b_feat, w_text, b_text, w1,
                                                       Wfx, Wtx, bpre);
    deg_k<<<(NE + 255) / 256, 256, 0, stream>>>(ei, deg);
    dinv_k<<<(NN + 255) / 256, 256, 0, stream>>>(deg, dinv);
    gemm1_k<<<(NN + 127) / 128, 128, 0, stream>>>(x, txt, Wfx, Wtx, bpre, dinv, u1);
    scat1_k<<<(NE + 15) / 16, 256, 0, stream>>>(ei, u1, agg1);
    post1_k<<<(NN + 3) / 4, 256, 0, stream>>>(agg1, u1, dinv, b1, w2, u2);
    scat2_k<<<(NE + 127) / 128, 256, 0, stream>>>(ei, u2, agg2);
    final_k<<<(NN * 7 + 255) / 256, 256, 0, stream>>>(agg2, u2, dinv, b2, out);
}

// Round 2
// 583.677 us; speedup vs baseline: 1.2523x; 1.2523x over previous
//
#include <hip/hip_runtime.h>

#define NN 100000
#define NE 1280000
#define K_FEAT 500
#define K_TEXT 384
#define KP_FEAT 512
#define KP_TEXT 384
#define H 64
#define BM 128

typedef unsigned short ushort_t;
typedef __attribute__((ext_vector_type(8))) short bf16x8;
typedef __attribute__((ext_vector_type(4))) float f32x4;

__device__ __forceinline__ ushort_t f2bf(float f) {
    union { float f; unsigned int u; } v; v.f = f;
    unsigned int r = (v.u + 0x7FFFu + ((v.u >> 16) & 1u)) >> 16;  // RNE
    return (ushort_t)r;
}

// ---------------- weight fusion: WfxT[c][k] = (w_feat @ w1_top)^T in bf16 (padded),
// WtxT[c][k] = (w_text @ w1_bot)^T in bf16, bpre = b_feat@w1_top + b_text@w1_bot ----------------
__global__ void fuse_k(const float* __restrict__ wf, const float* __restrict__ bf,
                       const float* __restrict__ wt, const float* __restrict__ bt,
                       const float* __restrict__ w1,
                       ushort_t* __restrict__ WfxT, ushort_t* __restrict__ WtxT,
                       float* __restrict__ bpre) {
    const int idx = blockIdx.x * 256 + threadIdx.x;
    const int T1 = H * KP_FEAT;
    const int T2 = T1 + H * KP_TEXT;
    if (idx < T1) {
        const int c = idx >> 9, k = idx & 511;
        float s = 0.f;
        if (k < K_FEAT) {
            #pragma unroll 8
            for (int u = 0; u < 64; ++u) s = fmaf(wf[k * 64 + u], w1[u * 64 + c], s);
        }
        WfxT[idx] = f2bf(s);
    } else if (idx < T2) {
        const int r = idx - T1;
        const int c = r / KP_TEXT, k = r - c * KP_TEXT;
        float s = 0.f;
        #pragma unroll 8
        for (int u = 0; u < 64; ++u) s = fmaf(wt[k * 64 + u], w1[(64 + u) * 64 + c], s);
        WtxT[r] = f2bf(s);
    } else if (idx < T2 + H) {
        const int j = idx - T2;
        float s = 0.f;
        for (int u = 0; u < 64; ++u) s = fmaf(bf[u], w1[u * 64 + j], s);
        for (int u = 0; u < 64; ++u) s = fmaf(bt[u], w1[(64 + u) * 64 + j], s);
        bpre[j] = s;
    }
}

// ---------------- degree / dinv ----------------
__global__ void deg_k(const int* __restrict__ ei, int* __restrict__ deg) {
    const int e = blockIdx.x * 256 + threadIdx.x;
    if (e < NE) atomicAdd(&deg[ei[NE + e]], 1);
}

__global__ void dinv_k(const int* __restrict__ deg, float* __restrict__ dinv) {
    const int i = blockIdx.x * 256 + threadIdx.x;
    if (i < NN) dinv[i] = rsqrtf((float)deg[i] + 1.0f);
}

// ---------------- GEMM1 (MFMA bf16): u1[N,64] = (x@Wfx + txt@Wtx + bpre) * dinv[row] ----------------
// 256 thr / 4 waves; tile BM=128 x N=64, BK=64; wave w owns rows w*32..w*32+31 (2 row-frags x 4 col-frags).
// LDS XOR-swizzled (stride 128B rows would otherwise be a 16-way bank conflict).
__global__ __launch_bounds__(256)
void gemm1_mfma(const float* __restrict__ x, const float* __restrict__ txt,
                const ushort_t* __restrict__ WfxT, const ushort_t* __restrict__ WtxT,
                const float* __restrict__ bpre, const float* __restrict__ dinv,
                float* __restrict__ u1) {
    __shared__ ushort_t As[BM * 64];   // [row][k] bf16, 128B rows, swizzled
    __shared__ ushort_t Bs[H * 64];    // [col][k] bf16, 128B rows, swizzled
    char* const baseA = (char*)As;
    char* const baseB = (char*)Bs;
    const int t = threadIdx.x;
    const int wave = t >> 6, lane = t & 63;
    const int row0 = blockIdx.x * BM;

    f32x4 acc[2][4];
    #pragma unroll
    for (int i = 0; i < 2; ++i)
        #pragma unroll
        for (int j = 0; j < 4; ++j) acc[i][j] = (f32x4){0.f, 0.f, 0.f, 0.f};

    const int ra = t >> 2;        // A staging: row within pass (0..63), 2 passes
    const int kqa = t & 3;        // 16-float chunk within the 64-wide k tile
    const int lr = lane & 15;     // fragment row/col selector
    const int lk = (lane >> 4) * 8;

    auto tileloop = [&](const float* __restrict__ A, const int Kdim,
                        const ushort_t* __restrict__ WT, const int KP, const int ntile) {
        for (int kt = 0; kt < ntile; ++kt) {
            const int k0 = kt * 64;
            // ---- stage A: 128 rows x 64 k fp32 -> bf16 LDS (2 passes of 64 rows) ----
            #pragma unroll
            for (int p = 0; p < 2; ++p) {
                const int rr = ra + p * 64;
                const int grow = row0 + rr;
                ushort_t tmp[16];
                #pragma unroll
                for (int i = 0; i < 4; ++i) {
                    const int k = k0 + kqa * 16 + i * 4;
                    float4 v = make_float4(0.f, 0.f, 0.f, 0.f);
                    if (grow < NN && k + 3 < Kdim)
                        v = *reinterpret_cast<const float4*>(&A[(long)grow * Kdim + k]);
                    tmp[i * 4 + 0] = f2bf(v.x); tmp[i * 4 + 1] = f2bf(v.y);
                    tmp[i * 4 + 2] = f2bf(v.z); tmp[i * 4 + 3] = f2bf(v.w);
                }
                const int sw = (rr & 7) << 4;
                *(bf16x8*)(baseA + ((rr * 128 + kqa * 32) ^ sw)) = *(bf16x8*)&tmp[0];
                *(bf16x8*)(baseA + ((rr * 128 + kqa * 32 + 16) ^ sw)) = *(bf16x8*)&tmp[8];
            }
            // ---- stage B: 64 cols x 64 k bf16 (already transposed+padded in global) ----
            {
                const int c = t >> 2;
                const int kqb = t & 3;
                const ushort_t* srcB = WT + (long)c * KP + k0 + kqb * 16;
                bf16x8 b0 = *(const bf16x8*)(srcB);
                bf16x8 b1 = *(const bf16x8*)(srcB + 8);
                const int swb = (c & 7) << 4;
                *(bf16x8*)(baseB + ((c * 128 + kqb * 32) ^ swb)) = b0;
                *(bf16x8*)(baseB + ((c * 128 + kqb * 32 + 16) ^ swb)) = b1;
            }
            __syncthreads();
            // ---- compute: 2 k-steps of 32 ----
            #pragma unroll
            for (int ks = 0; ks < 2; ++ks) {
                const int kb = (ks * 32 + lk) * 2;   // byte offset in 128B row
                bf16x8 af[2];
                #pragma unroll
                for (int rf = 0; rf < 2; ++rf) {
                    const int r2 = wave * 32 + rf * 16 + lr;
                    af[rf] = *(const bf16x8*)(baseA + ((r2 * 128 + kb) ^ ((r2 & 7) << 4)));
                }
                bf16x8 bfr[4];
                #pragma unroll
                for (int cf = 0; cf < 4; ++cf) {
                    const int c2 = cf * 16 + lr;
                    bfr[cf] = *(const bf16x8*)(baseB + ((c2 * 128 + kb) ^ ((c2 & 7) << 4)));
                }
                #pragma unroll
                for (int rf = 0; rf < 2; ++rf)
                    #pragma unroll
                    for (int cf = 0; cf < 4; ++cf)
                        acc[rf][cf] = __builtin_amdgcn_mfma_f32_16x16x32_bf16(
                            af[rf], bfr[cf], acc[rf][cf], 0, 0, 0);
            }
            __syncthreads();
        }
    };
    tileloop(x, K_FEAT, WfxT, KP_FEAT, 8);
    tileloop(txt, K_TEXT, WtxT, KP_TEXT, 6);

    // ---- epilogue: D frag layout col=lane&15, row=(lane>>4)*4+reg ----
    #pragma unroll
    for (int rf = 0; rf < 2; ++rf) {
        #pragma unroll
        for (int reg = 0; reg < 4; ++reg) {
            const int r = row0 + wave * 32 + rf * 16 + (lane >> 4) * 4 + reg;
            if (r < NN) {
                const float di = dinv[r];
                #pragma unroll
                for (int cf = 0; cf < 4; ++cf) {
                    const int c = cf * 16 + lr;
                    u1[(long)r * H + c] = (acc[rf][cf][reg] + bpre[c]) * di;
                }
            }
        }
    }
}

// ---------------- scatter layer 1: agg1[dst] += u1[src], 64 ch, 4 edges per wave ----------------
__global__ __launch_bounds__(256)
void scat1_k(const int* __restrict__ ei, const float* __restrict__ u1,
             float* __restrict__ agg1) {
    const int lane = threadIdx.x & 63;
    const int wid = blockIdx.x * 4 + (threadIdx.x >> 6);
    const int e0 = wid * 4;
    #pragma unroll
    for (int i = 0; i < 4; ++i) {
        const int e = e0 + i;
        if (e < NE) {
            const int s = ei[e];
            const int d = ei[NE + e];
            const float v = u1[(long)s * H + lane];
            unsafeAtomicAdd(&agg1[(long)d * H + lane], v);
        }
    }
}

// ---------------- post layer1 + GEMM2: u2[N,8] = dinv * (relu(dinv*(agg1+u1)+b1) @ w2) ----------------
__global__ __launch_bounds__(256)
void post1_k(const float* __restrict__ agg1, const float* __restrict__ u1,
             const float* __restrict__ dinv, const float* __restrict__ b1,
             const float* __restrict__ w2, float* __restrict__ u2) {
    const int lane = threadIdx.x & 63;
    const int row = blockIdx.x * 4 + (threadIdx.x >> 6);
    if (row >= NN) return;
    const float di = dinv[row];
    float h = di * (agg1[(long)row * H + lane] + u1[(long)row * H + lane]) + b1[lane];
    h = fmaxf(h, 0.f);
    #pragma unroll
    for (int j = 0; j < 7; ++j) {
        float s = h * w2[lane * 7 + j];
        #pragma unroll
        for (int m = 1; m < 64; m <<= 1) s += __shfl_xor(s, m, 64);
        if (lane == j) u2[row * 8 + j] = di * s;
    }
}

// ---------------- scatter layer 2: agg2[dst] += u2[src], 7 ch ----------------
__global__ __launch_bounds__(256)
void scat2_k(const int* __restrict__ ei, const float* __restrict__ u2,
             float* __restrict__ agg2) {
    const int c = threadIdx.x & 7;
    const int g = blockIdx.x * 32 + (threadIdx.x >> 3);
    const int e0 = g * 4;
    #pragma unroll
    for (int i = 0; i < 4; ++i) {
        const int e = e0 + i;
        if (e < NE && c < 7) {
            const int s = ei[e];
            const int d = ei[NE + e];
            unsafeAtomicAdd(&agg2[d * 8 + c], u2[s * 8 + c]);
        }
    }
}

// ---------------- final: out = dinv*(agg2+u2) + b2 ----------------
__global__ void final_k(const float* __restrict__ agg2, const float* __restrict__ u2,
                        const float* __restrict__ dinv, const float* __restrict__ b2,
                        float* __restrict__ out) {
    const int idx = blockIdx.x * 256 + threadIdx.x;
    if (idx < NN * 7) {
        const int row = idx / 7;
        const int j = idx - row * 7;
        out[idx] = dinv[row] * (agg2[row * 8 + j] + u2[row * 8 + j]) + b2[j];
    }
}

extern "C" void kernel_launch(void* const* d_in, const int* in_sizes, int n_in,
                              void* d_out, int out_size, void* d_ws, size_t ws_size,
                              hipStream_t stream) {
    const float* x      = (const float*)d_in[0];
    const float* txt    = (const float*)d_in[1];
    const int*   ei     = (const int*)d_in[2];
    const float* w_feat = (const float*)d_in[3];
    const float* b_feat = (const float*)d_in[4];
    const float* w_text = (const float*)d_in[5];
    const float* b_text = (const float*)d_in[6];
    const float* w1     = (const float*)d_in[7];
    const float* b1     = (const float*)d_in[8];
    const float* w2     = (const float*)d_in[9];
    const float* b2     = (const float*)d_in[10];
    float* out = (float*)d_out;

    char* p = (char*)d_ws;
    auto alloc = [&](size_t bytes) {
        char* r = p;
        p += (bytes + 255) & ~(size_t)255;
        return r;
    };
    ushort_t* WfxT = (ushort_t*)alloc((size_t)H * KP_FEAT * 2);
    ushort_t* WtxT = (ushort_t*)alloc((size_t)H * KP_TEXT * 2);
    float* bpre = (float*)alloc(H * 4);
    int*   deg  = (int*)alloc((size_t)NN * 4);
    float* dinv = (float*)alloc((size_t)NN * 4);
    float* u1   = (float*)alloc((size_t)NN * H * 4);
    float* agg1 = (float*)alloc((size_t)NN * H * 4);
    float* u2   = (float*)alloc((size_t)NN * 8 * 4);
    float* agg2 = (float*)alloc((size_t)NN * 8 * 4);

    hipMemsetAsync(deg, 0, (size_t)NN * 4, stream);
    hipMemsetAsync(agg1, 0, (size_t)NN * H * 4, stream);
    hipMemsetAsync(agg2, 0, (size_t)NN * 8 * 4, stream);

    const int fuse_tot = H * KP_FEAT + H * KP_TEXT + H;
    fuse_k<<<(fuse_tot + 255) / 256, 256, 0, stream>>>(w_feat, b_feat, w_text, b_text, w1,
                                                       WfxT, WtxT, bpre);
    deg_k<<<(NE + 255) / 256, 256, 0, stream>>>(ei, deg);
    dinv_k<<<(NN + 255) / 256, 256, 0, stream>>>(deg, dinv);
    gemm1_mfma<<<(NN + BM - 1) / BM, 256, 0, stream>>>(x, txt, WfxT, WtxT, bpre, dinv, u1);
    scat1_k<<<(NE + 15) / 16, 256, 0, stream>>>(ei, u1, agg1);
    post1_k<<<(NN + 3) / 4, 256, 0, stream>>>(agg1, u1, dinv, b1, w2, u2);
    scat2_k<<<(NE + 127) / 128, 256, 0, stream>>>(ei, u2, agg2);
    final_k<<<(NN * 7 + 255) / 256, 256, 0, stream>>>(agg2, u2, dinv, b2, out);
}

// Round 3
// 395.817 us; speedup vs baseline: 1.8466x; 1.4746x over previous
//
#include <hip/hip_runtime.h>

#define NN 100000
#define NE 1280000
#define K_FEAT 500
#define K_TEXT 384
#define KP_FEAT 512
#define KP_TEXT 384
#define H 64
#define BM 128
#define SCAN_BLOCKS 100
#define NODES_PER_SCAN 1000

typedef unsigned short ushort_t;
typedef __attribute__((ext_vector_type(8))) short bf16x8;
typedef __attribute__((ext_vector_type(4))) float f32x4;

__device__ __forceinline__ ushort_t f2bf(float f) {
    union { float f; unsigned int u; } v; v.f = f;
    unsigned int r = (v.u + 0x7FFFu + ((v.u >> 16) & 1u)) >> 16;  // RNE
    return (ushort_t)r;
}

// ---------------- weight fusion (pre-transposed bf16) ----------------
__global__ void fuse_k(const float* __restrict__ wf, const float* __restrict__ bf,
                       const float* __restrict__ wt, const float* __restrict__ bt,
                       const float* __restrict__ w1,
                       ushort_t* __restrict__ WfxT, ushort_t* __restrict__ WtxT,
                       float* __restrict__ bpre) {
    const int idx = blockIdx.x * 256 + threadIdx.x;
    const int T1 = H * KP_FEAT;
    const int T2 = T1 + H * KP_TEXT;
    if (idx < T1) {
        const int c = idx >> 9, k = idx & 511;
        float s = 0.f;
        if (k < K_FEAT) {
            #pragma unroll 8
            for (int u = 0; u < 64; ++u) s = fmaf(wf[k * 64 + u], w1[u * 64 + c], s);
        }
        WfxT[idx] = f2bf(s);
    } else if (idx < T2) {
        const int r = idx - T1;
        const int c = r / KP_TEXT, k = r - c * KP_TEXT;
        float s = 0.f;
        #pragma unroll 8
        for (int u = 0; u < 64; ++u) s = fmaf(wt[k * 64 + u], w1[(64 + u) * 64 + c], s);
        WtxT[r] = f2bf(s);
    } else if (idx < T2 + H) {
        const int j = idx - T2;
        float s = 0.f;
        for (int u = 0; u < 64; ++u) s = fmaf(bf[u], w1[u * 64 + j], s);
        for (int u = 0; u < 64; ++u) s = fmaf(bt[u], w1[(64 + u) * 64 + j], s);
        bpre[j] = s;
    }
}

// ---------------- degree (edge count per dst) ----------------
__global__ void deg_k(const int* __restrict__ ei, int* __restrict__ deg) {
    const int e = blockIdx.x * 256 + threadIdx.x;
    if (e < NE) atomicAdd(&deg[ei[NE + e]], 1);
}

__global__ void dinv_k(const int* __restrict__ deg, float* __restrict__ dinv) {
    const int i = blockIdx.x * 256 + threadIdx.x;
    if (i < NN) dinv[i] = rsqrtf((float)deg[i] + 1.0f);
}

// ---------------- CSR build: partial sums -> scan partials -> offsets+cursor ----------------
__global__ __launch_bounds__(256)
void partial_k(const int* __restrict__ deg, int* __restrict__ partial) {
    const int b = blockIdx.x;
    const int base = b * NODES_PER_SCAN;
    const int t = threadIdx.x;
    int s = 0;
    for (int i = t; i < NODES_PER_SCAN; i += 256) s += deg[base + i];
    #pragma unroll
    for (int m = 1; m < 64; m <<= 1) s += __shfl_xor(s, m, 64);
    __shared__ int ws[4];
    if ((t & 63) == 0) ws[t >> 6] = s;
    __syncthreads();
    if (t == 0) partial[b] = ws[0] + ws[1] + ws[2] + ws[3];
}

__global__ void scanp_k(const int* __restrict__ partial, int* __restrict__ psum) {
    __shared__ int buf[SCAN_BLOCKS];
    const int t = threadIdx.x;
    if (t < SCAN_BLOCKS) buf[t] = partial[t];
    __syncthreads();
    if (t == 0) {
        int run = 0;
        for (int i = 0; i < SCAN_BLOCKS; ++i) { int v = buf[i]; buf[i] = run; run += v; }
    }
    __syncthreads();
    if (t < SCAN_BLOCKS) psum[t] = buf[t];
}

__global__ __launch_bounds__(256)
void offsets_k(const int* __restrict__ deg, const int* __restrict__ psum,
               int* __restrict__ row_start, int* __restrict__ cursor) {
    const int b = blockIdx.x;
    const int base = b * NODES_PER_SCAN;
    const int t = threadIdx.x;
    __shared__ int tsum[256];
    int loc[4];
    int s = 0;
    #pragma unroll
    for (int i = 0; i < 4; ++i) {
        loc[i] = s;
        const int n = t * 4 + i;
        if (n < NODES_PER_SCAN) s += deg[base + n];
    }
    tsum[t] = s;
    __syncthreads();
    #pragma unroll
    for (int off = 1; off < 256; off <<= 1) {
        int v = (t >= off) ? tsum[t - off] : 0;
        __syncthreads();
        tsum[t] += v;
        __syncthreads();
    }
    const int texcl = (t == 0) ? 0 : tsum[t - 1];
    const int bp = psum[b];
    #pragma unroll
    for (int i = 0; i < 4; ++i) {
        const int n = t * 4 + i;
        if (n < NODES_PER_SCAN) {
            const int rs = bp + texcl + loc[i];
            row_start[base + n] = rs;
            cursor[base + n] = rs;
        }
    }
}

__global__ void sort_k(const int* __restrict__ ei, int* __restrict__ cursor,
                       int* __restrict__ src_sorted) {
    const int e = blockIdx.x * 256 + threadIdx.x;
    if (e < NE) {
        const int s = ei[e];
        const int d = ei[NE + e];
        const int pos = atomicAdd(&cursor[d], 1);
        src_sorted[pos] = s;
    }
}

// ---------------- GEMM1 (MFMA bf16): u1[N,64] = (x@Wfx + txt@Wtx + bpre) * dinv[row] ----------------
__global__ __launch_bounds__(256)
void gemm1_mfma(const float* __restrict__ x, const float* __restrict__ txt,
                const ushort_t* __restrict__ WfxT, const ushort_t* __restrict__ WtxT,
                const float* __restrict__ bpre, const float* __restrict__ dinv,
                float* __restrict__ u1) {
    __shared__ ushort_t As[BM * 64];
    __shared__ ushort_t Bs[H * 64];
    char* const baseA = (char*)As;
    char* const baseB = (char*)Bs;
    const int t = threadIdx.x;
    const int wave = t >> 6, lane = t & 63;
    const int row0 = blockIdx.x * BM;

    f32x4 acc[2][4];
    #pragma unroll
    for (int i = 0; i < 2; ++i)
        #pragma unroll
        for (int j = 0; j < 4; ++j) acc[i][j] = (f32x4){0.f, 0.f, 0.f, 0.f};

    const int ra = t >> 2;
    const int kqa = t & 3;
    const int lr = lane & 15;
    const int lk = (lane >> 4) * 8;

    auto tileloop = [&](const float* __restrict__ A, const int Kdim,
                        const ushort_t* __restrict__ WT, const int KP, const int ntile) {
        for (int kt = 0; kt < ntile; ++kt) {
            const int k0 = kt * 64;
            #pragma unroll
            for (int p = 0; p < 2; ++p) {
                const int rr = ra + p * 64;
                const int grow = row0 + rr;
                ushort_t tmp[16];
                #pragma unroll
                for (int i = 0; i < 4; ++i) {
                    const int k = k0 + kqa * 16 + i * 4;
                    float4 v = make_float4(0.f, 0.f, 0.f, 0.f);
                    if (grow < NN && k + 3 < Kdim)
                        v = *reinterpret_cast<const float4*>(&A[(long)grow * Kdim + k]);
                    tmp[i * 4 + 0] = f2bf(v.x); tmp[i * 4 + 1] = f2bf(v.y);
                    tmp[i * 4 + 2] = f2bf(v.z); tmp[i * 4 + 3] = f2bf(v.w);
                }
                const int sw = (rr & 7) << 4;
                *(bf16x8*)(baseA + ((rr * 128 + kqa * 32) ^ sw)) = *(bf16x8*)&tmp[0];
                *(bf16x8*)(baseA + ((rr * 128 + kqa * 32 + 16) ^ sw)) = *(bf16x8*)&tmp[8];
            }
            {
                const int c = t >> 2;
                const int kqb = t & 3;
                const ushort_t* srcB = WT + (long)c * KP + k0 + kqb * 16;
                bf16x8 b0 = *(const bf16x8*)(srcB);
                bf16x8 b1 = *(const bf16x8*)(srcB + 8);
                const int swb = (c & 7) << 4;
                *(bf16x8*)(baseB + ((c * 128 + kqb * 32) ^ swb)) = b0;
                *(bf16x8*)(baseB + ((c * 128 + kqb * 32 + 16) ^ swb)) = b1;
            }
            __syncthreads();
            #pragma unroll
            for (int ks = 0; ks < 2; ++ks) {
                const int kb = (ks * 32 + lk) * 2;
                bf16x8 af[2];
                #pragma unroll
                for (int rf = 0; rf < 2; ++rf) {
                    const int r2 = wave * 32 + rf * 16 + lr;
                    af[rf] = *(const bf16x8*)(baseA + ((r2 * 128 + kb) ^ ((r2 & 7) << 4)));
                }
                bf16x8 bfr[4];
                #pragma unroll
                for (int cf = 0; cf < 4; ++cf) {
                    const int c2 = cf * 16 + lr;
                    bfr[cf] = *(const bf16x8*)(baseB + ((c2 * 128 + kb) ^ ((c2 & 7) << 4)));
                }
                #pragma unroll
                for (int rf = 0; rf < 2; ++rf)
                    #pragma unroll
                    for (int cf = 0; cf < 4; ++cf)
                        acc[rf][cf] = __builtin_amdgcn_mfma_f32_16x16x32_bf16(
                            af[rf], bfr[cf], acc[rf][cf], 0, 0, 0);
            }
            __syncthreads();
        }
    };
    tileloop(x, K_FEAT, WfxT, KP_FEAT, 8);
    tileloop(txt, K_TEXT, WtxT, KP_TEXT, 6);

    #pragma unroll
    for (int rf = 0; rf < 2; ++rf) {
        #pragma unroll
        for (int reg = 0; reg < 4; ++reg) {
            const int r = row0 + wave * 32 + rf * 16 + (lane >> 4) * 4 + reg;
            if (r < NN) {
                const float di = dinv[r];
                #pragma unroll
                for (int cf = 0; cf < 4; ++cf) {
                    const int c = cf * 16 + lr;
                    u1[(long)r * H + c] = (acc[rf][cf][reg] + bpre[c]) * di;
                }
            }
        }
    }
}

// ---------------- layer1: CSR gather-aggregate + relu + 64->7 projection ----------------
// wave per node, lane = channel. acc includes self term.
__global__ __launch_bounds__(256)
void layer1_csr_k(const int* __restrict__ row_start, const int* __restrict__ deg,
                  const int* __restrict__ src_sorted, const float* __restrict__ u1,
                  const float* __restrict__ dinv, const float* __restrict__ b1,
                  const float* __restrict__ w2, float* __restrict__ u2) {
    const int t = threadIdx.x;
    const int lane = t & 63;
    const int node = blockIdx.x * 4 + (t >> 6);
    if (node >= NN) return;
    const int rs = row_start[node];
    const int dg = deg[node];
    float acc = u1[(long)node * H + lane];   // self
    for (int j0 = 0; j0 < dg; j0 += 64) {
        const int nj = min(64, dg - j0);
        int sv = 0;
        if (lane < nj) sv = src_sorted[rs + j0 + lane];
        int j = 0;
        for (; j + 4 <= nj; j += 4) {
            const int s0 = __shfl(sv, j, 64);
            const int s1 = __shfl(sv, j + 1, 64);
            const int s2 = __shfl(sv, j + 2, 64);
            const int s3 = __shfl(sv, j + 3, 64);
            const float v0 = u1[(long)s0 * H + lane];
            const float v1 = u1[(long)s1 * H + lane];
            const float v2 = u1[(long)s2 * H + lane];
            const float v3 = u1[(long)s3 * H + lane];
            acc += v0; acc += v1; acc += v2; acc += v3;
        }
        for (; j < nj; ++j) {
            const int s = __shfl(sv, j, 64);
            acc += u1[(long)s * H + lane];
        }
    }
    const float di = dinv[node];
    const float h = fmaxf(di * acc + b1[lane], 0.f);
    #pragma unroll
    for (int j = 0; j < 7; ++j) {
        float s = h * w2[lane * 7 + j];
        #pragma unroll
        for (int m = 1; m < 64; m <<= 1) s += __shfl_xor(s, m, 64);
        if (lane == j) u2[node * 8 + j] = di * s;
    }
}

// ---------------- layer2: CSR gather-aggregate + final transform ----------------
// 8 threads per node (c = 0..7, c<7 active)
__global__ __launch_bounds__(256)
void layer2_csr_k(const int* __restrict__ row_start, const int* __restrict__ deg,
                  const int* __restrict__ src_sorted, const float* __restrict__ u2,
                  const float* __restrict__ dinv, const float* __restrict__ b2,
                  float* __restrict__ out) {
    const int t = threadIdx.x;
    const int c = t & 7;
    const int node = blockIdx.x * 32 + (t >> 3);
    if (node >= NN) return;
    const int rs = row_start[node];
    const int dg = deg[node];
    float acc = (c < 7) ? u2[node * 8 + c] : 0.f;   // self
    int j = 0;
    for (; j + 4 <= dg; j += 4) {
        const int s0 = src_sorted[rs + j];
        const int s1 = src_sorted[rs + j + 1];
        const int s2 = src_sorted[rs + j + 2];
        const int s3 = src_sorted[rs + j + 3];
        if (c < 7) {
            acc += u2[s0 * 8 + c];
            acc += u2[s1 * 8 + c];
            acc += u2[s2 * 8 + c];
            acc += u2[s3 * 8 + c];
        }
    }
    for (; j < dg; ++j) {
        const int s = src_sorted[rs + j];
        if (c < 7) acc += u2[s * 8 + c];
    }
    if (c < 7) out[node * 7 + c] = dinv[node] * acc + b2[c];
}

extern "C" void kernel_launch(void* const* d_in, const int* in_sizes, int n_in,
                              void* d_out, int out_size, void* d_ws, size_t ws_size,
                              hipStream_t stream) {
    const float* x      = (const float*)d_in[0];
    const float* txt    = (const float*)d_in[1];
    const int*   ei     = (const int*)d_in[2];
    const float* w_feat = (const float*)d_in[3];
    const float* b_feat = (const float*)d_in[4];
    const float* w_text = (const float*)d_in[5];
    const float* b_text = (const float*)d_in[6];
    const float* w1     = (const float*)d_in[7];
    const float* b1     = (const float*)d_in[8];
    const float* w2     = (const float*)d_in[9];
    const float* b2     = (const float*)d_in[10];
    float* out = (float*)d_out;

    char* p = (char*)d_ws;
    auto alloc = [&](size_t bytes) {
        char* r = p;
        p += (bytes + 255) & ~(size_t)255;
        return r;
    };
    ushort_t* WfxT = (ushort_t*)alloc((size_t)H * KP_FEAT * 2);
    ushort_t* WtxT = (ushort_t*)alloc((size_t)H * KP_TEXT * 2);
    float* bpre = (float*)alloc(H * 4);
    int*   deg  = (int*)alloc((size_t)NN * 4);
    float* dinv = (float*)alloc((size_t)NN * 4);
    int*   row_start = (int*)alloc((size_t)NN * 4);
    int*   cursor    = (int*)alloc((size_t)NN * 4);
    int*   partial   = (int*)alloc((size_t)SCAN_BLOCKS * 4);
    int*   psum      = (int*)alloc((size_t)SCAN_BLOCKS * 4);
    int*   src_sorted = (int*)alloc((size_t)NE * 4);
    float* u1   = (float*)alloc((size_t)NN * H * 4);
    float* u2   = (float*)alloc((size_t)NN * 8 * 4);

    hipMemsetAsync(deg, 0, (size_t)NN * 4, stream);

    const int fuse_tot = H * KP_FEAT + H * KP_TEXT + H;
    fuse_k<<<(fuse_tot + 255) / 256, 256, 0, stream>>>(w_feat, b_feat, w_text, b_text, w1,
                                                       WfxT, WtxT, bpre);
    deg_k<<<(NE + 255) / 256, 256, 0, stream>>>(ei, deg);
    dinv_k<<<(NN + 255) / 256, 256, 0, stream>>>(deg, dinv);
    partial_k<<<SCAN_BLOCKS, 256, 0, stream>>>(deg, partial);
    scanp_k<<<1, 128, 0, stream>>>(partial, psum);
    offsets_k<<<SCAN_BLOCKS, 256, 0, stream>>>(deg, psum, row_start, cursor);
    sort_k<<<(NE + 255) / 256, 256, 0, stream>>>(ei, cursor, src_sorted);
    gemm1_mfma<<<(NN + BM - 1) / BM, 256, 0, stream>>>(x, txt, WfxT, WtxT, bpre, dinv, u1);
    layer1_csr_k<<<(NN + 3) / 4, 256, 0, stream>>>(row_start, deg, src_sorted, u1,
                                                   dinv, b1, w2, u2);
    layer2_csr_k<<<(NN + 31) / 32, 256, 0, stream>>>(row_start, deg, src_sorted, u2,
                                                     dinv, b2, out);
}

// Round 4
// 393.307 us; speedup vs baseline: 1.8584x; 1.0064x over previous
//
#include <hip/hip_runtime.h>

#define NN 100000
#define NE 1280000
#define K_FEAT 500
#define K_TEXT 384
#define KP 512
#define H 64
#define BM 128
#define SCAN_BLOCKS 100
#define NODES_PER_SCAN 1000

typedef unsigned short ushort_t;
typedef __attribute__((ext_vector_type(8))) short bf16x8;
typedef __attribute__((ext_vector_type(4))) float f32x4;

template <int V> struct IC { static constexpr int value = V; };

__device__ __forceinline__ ushort_t f2bf(float f) {
    union { float f; unsigned int u; } v; v.f = f;
    unsigned int r = (v.u + 0x7FFFu + ((v.u >> 16) & 1u)) >> 16;  // RNE
    return (ushort_t)r;
}

// pack 8 f32 -> 8 bf16 via hardware cvt_pk (RNE)
__device__ __forceinline__ bf16x8 cvt8(float4 a, float4 b) {
    union { bf16x8 v; unsigned int w[4]; } u;
    asm("v_cvt_pk_bf16_f32 %0, %1, %2" : "=v"(u.w[0]) : "v"(a.x), "v"(a.y));
    asm("v_cvt_pk_bf16_f32 %0, %1, %2" : "=v"(u.w[1]) : "v"(a.z), "v"(a.w));
    asm("v_cvt_pk_bf16_f32 %0, %1, %2" : "=v"(u.w[2]) : "v"(b.x), "v"(b.y));
    asm("v_cvt_pk_bf16_f32 %0, %1, %2" : "=v"(u.w[3]) : "v"(b.z), "v"(b.w));
    return u.v;
}

// ---------------- weight fusion (pre-transposed bf16, both padded to [64][512]) ----------------
__global__ void fuse_k(const float* __restrict__ wf, const float* __restrict__ bf,
                       const float* __restrict__ wt, const float* __restrict__ bt,
                       const float* __restrict__ w1,
                       ushort_t* __restrict__ WfxT, ushort_t* __restrict__ WtxT,
                       float* __restrict__ bpre) {
    const int idx = blockIdx.x * 256 + threadIdx.x;
    const int T1 = H * KP;
    const int T2 = 2 * T1;
    if (idx < T1) {
        const int c = idx >> 9, k = idx & 511;
        float s = 0.f;
        if (k < K_FEAT) {
            #pragma unroll 8
            for (int u = 0; u < 64; ++u) s = fmaf(wf[k * 64 + u], w1[u * 64 + c], s);
        }
        WfxT[idx] = f2bf(s);
    } else if (idx < T2) {
        const int r = idx - T1;
        const int c = r >> 9, k = r & 511;
        float s = 0.f;
        if (k < K_TEXT) {
            #pragma unroll 8
            for (int u = 0; u < 64; ++u) s = fmaf(wt[k * 64 + u], w1[(64 + u) * 64 + c], s);
        }
        WtxT[r] = f2bf(s);
    } else if (idx < T2 + H) {
        const int j = idx - T2;
        float s = 0.f;
        for (int u = 0; u < 64; ++u) s = fmaf(bf[u], w1[u * 64 + j], s);
        for (int u = 0; u < 64; ++u) s = fmaf(bt[u], w1[(64 + u) * 64 + j], s);
        bpre[j] = s;
    }
}

// ---------------- degree / dinv ----------------
__global__ void deg_k(const int* __restrict__ ei, int* __restrict__ deg) {
    const int e = blockIdx.x * 256 + threadIdx.x;
    if (e < NE) atomicAdd(&deg[ei[NE + e]], 1);
}

__global__ void dinv_k(const int* __restrict__ deg, float* __restrict__ dinv) {
    const int i = blockIdx.x * 256 + threadIdx.x;
    if (i < NN) dinv[i] = rsqrtf((float)deg[i] + 1.0f);
}

// ---------------- CSR build ----------------
__global__ __launch_bounds__(256)
void partial_k(const int* __restrict__ deg, int* __restrict__ partial) {
    const int b = blockIdx.x;
    const int base = b * NODES_PER_SCAN;
    const int t = threadIdx.x;
    int s = 0;
    for (int i = t; i < NODES_PER_SCAN; i += 256) s += deg[base + i];
    #pragma unroll
    for (int m = 1; m < 64; m <<= 1) s += __shfl_xor(s, m, 64);
    __shared__ int ws[4];
    if ((t & 63) == 0) ws[t >> 6] = s;
    __syncthreads();
    if (t == 0) partial[b] = ws[0] + ws[1] + ws[2] + ws[3];
}

__global__ void scanp_k(const int* __restrict__ partial, int* __restrict__ psum) {
    __shared__ int buf[SCAN_BLOCKS];
    const int t = threadIdx.x;
    if (t < SCAN_BLOCKS) buf[t] = partial[t];
    __syncthreads();
    if (t == 0) {
        int run = 0;
        for (int i = 0; i < SCAN_BLOCKS; ++i) { int v = buf[i]; buf[i] = run; run += v; }
    }
    __syncthreads();
    if (t < SCAN_BLOCKS) psum[t] = buf[t];
}

__global__ __launch_bounds__(256)
void offsets_k(const int* __restrict__ deg, const int* __restrict__ psum,
               int* __restrict__ row_start, int* __restrict__ cursor) {
    const int b = blockIdx.x;
    const int base = b * NODES_PER_SCAN;
    const int t = threadIdx.x;
    __shared__ int tsum[256];
    int loc[4];
    int s = 0;
    #pragma unroll
    for (int i = 0; i < 4; ++i) {
        loc[i] = s;
        const int n = t * 4 + i;
        if (n < NODES_PER_SCAN) s += deg[base + n];
    }
    tsum[t] = s;
    __syncthreads();
    #pragma unroll
    for (int off = 1; off < 256; off <<= 1) {
        int v = (t >= off) ? tsum[t - off] : 0;
        __syncthreads();
        tsum[t] += v;
        __syncthreads();
    }
    const int texcl = (t == 0) ? 0 : tsum[t - 1];
    const int bp = psum[b];
    #pragma unroll
    for (int i = 0; i < 4; ++i) {
        const int n = t * 4 + i;
        if (n < NODES_PER_SCAN) {
            const int rs = bp + texcl + loc[i];
            row_start[base + n] = rs;
            cursor[base + n] = rs;
        }
    }
}

__global__ void sort_k(const int* __restrict__ ei, int* __restrict__ cursor,
                       int* __restrict__ src_sorted) {
    const int e = blockIdx.x * 256 + threadIdx.x;
    if (e < NE) {
        const int s = ei[e];
        const int d = ei[NE + e];
        const int pos = atomicAdd(&cursor[d], 1);
        src_sorted[pos] = s;
    }
}

// ---------------- GEMM1 (MFMA bf16, barrier-free streaming A) ----------------
// u1[N,64] = (x@Wfx + txt@Wtx + bpre) * dinv[row]
// 4 waves/block, wave owns 32 rows. B ([64 cols][512 k] bf16, swizzled) preloaded
// to LDS once per phase; A fragments loaded per-lane directly from global and
// converted with v_cvt_pk_bf16_f32. No barriers inside the K loop.
__global__ __launch_bounds__(256)
void gemm1_mfma(const float* __restrict__ x, const float* __restrict__ txt,
                const ushort_t* __restrict__ WfxT, const ushort_t* __restrict__ WtxT,
                const float* __restrict__ bpre, const float* __restrict__ dinv,
                float* __restrict__ u1) {
    __shared__ ushort_t Bs[H * KP];     // 64 KB, [col][k], row stride 1024B, XOR-swizzled
    char* const baseB = (char*)Bs;
    const int t = threadIdx.x;
    const int wave = t >> 6, lane = t & 63;
    const int row0 = blockIdx.x * BM;
    const int lr = lane & 15;
    const int lq = lane >> 4;           // 0..3 -> k sub-offset lq*8

    f32x4 acc[2][4];
    #pragma unroll
    for (int i = 0; i < 2; ++i)
        #pragma unroll
        for (int j = 0; j < 4; ++j) acc[i][j] = (f32x4){0.f, 0.f, 0.f, 0.f};

    // clamped per-lane A row indices (epilogue predicates real writes)
    int rowi[2];
    rowi[0] = min(row0 + wave * 32 + lr, NN - 1);
    rowi[1] = min(row0 + wave * 32 + 16 + lr, NN - 1);

    auto preload = [&](const ushort_t* __restrict__ W) {
        #pragma unroll
        for (int i = 0; i < 16; ++i) {
            const int off = (t + i * 256) * 16;
            bf16x8 v = *(const bf16x8*)((const char*)W + off);
            *(bf16x8*)(baseB + (off ^ (((off >> 10) & 7) << 4))) = v;
        }
    };

    auto phase = [&](const float* __restrict__ A, auto KD, auto NT) {
        constexpr int KDIM = decltype(KD)::value;
        constexpr int NTILE = decltype(NT)::value;
        const float* p0 = A + (long)rowi[0] * KDIM + lq * 8;
        const float* p1 = A + (long)rowi[1] * KDIM + lq * 8;
        #pragma unroll
        for (int kt = 0; kt < NTILE; ++kt) {
            float4 c[2][2][2];   // [rf][ks][chunk]
            #pragma unroll
            for (int rf = 0; rf < 2; ++rf) {
                const float* p = rf ? p1 : p0;
                #pragma unroll
                for (int ks = 0; ks < 2; ++ks)
                    #pragma unroll
                    for (int ch = 0; ch < 2; ++ch) {
                        const int k = kt * 64 + ks * 32 + ch * 4;
                        if (KDIM % 64 == 0 || kt < NTILE - 1) {
                            c[rf][ks][ch] = *(const float4*)(p + k);
                        } else {
                            c[rf][ks][ch] = (k + lq * 8 < KDIM)
                                ? *(const float4*)(p + k)
                                : make_float4(0.f, 0.f, 0.f, 0.f);
                        }
                    }
            }
            #pragma unroll
            for (int ks = 0; ks < 2; ++ks) {
                bf16x8 af[2];
                #pragma unroll
                for (int rf = 0; rf < 2; ++rf)
                    af[rf] = cvt8(c[rf][ks][0], c[rf][ks][1]);
                bf16x8 bfr[4];
                #pragma unroll
                for (int cf = 0; cf < 4; ++cf) {
                    const int c2 = cf * 16 + lr;
                    const int byteoff = (c2 * KP + kt * 64 + ks * 32 + lq * 8) * 2;
                    bfr[cf] = *(const bf16x8*)(baseB + (byteoff ^ ((c2 & 7) << 4)));
                }
                #pragma unroll
                for (int rf = 0; rf < 2; ++rf)
                    #pragma unroll
                    for (int cf = 0; cf < 4; ++cf)
                        acc[rf][cf] = __builtin_amdgcn_mfma_f32_16x16x32_bf16(
                            af[rf], bfr[cf], acc[rf][cf], 0, 0, 0);
            }
        }
    };

    preload(WfxT);
    __syncthreads();
    phase(x, IC<K_FEAT>{}, IC<8>{});
    __syncthreads();               // all waves done with Wfx
    preload(WtxT);
    __syncthreads();
    phase(txt, IC<K_TEXT>{}, IC<6>{});

    // epilogue: D frag layout col=lane&15, row=(lane>>4)*4+reg
    #pragma unroll
    for (int rf = 0; rf < 2; ++rf) {
        #pragma unroll
        for (int reg = 0; reg < 4; ++reg) {
            const int r = row0 + wave * 32 + rf * 16 + lq * 4 + reg;
            if (r < NN) {
                const float di = dinv[r];
                #pragma unroll
                for (int cf = 0; cf < 4; ++cf) {
                    const int c = cf * 16 + lr;
                    u1[(long)r * H + c] = (acc[rf][cf][reg] + bpre[c]) * di;
                }
            }
        }
    }
}

// ---------------- layer1: CSR gather-aggregate + relu + 64->7 projection ----------------
__global__ __launch_bounds__(256)
void layer1_csr_k(const int* __restrict__ row_start, const int* __restrict__ deg,
                  const int* __restrict__ src_sorted, const float* __restrict__ u1,
                  const float* __restrict__ dinv, const float* __restrict__ b1,
                  const float* __restrict__ w2, float* __restrict__ u2) {
    const int t = threadIdx.x;
    const int lane = t & 63;
    const int node = blockIdx.x * 4 + (t >> 6);
    if (node >= NN) return;
    const int rs = row_start[node];
    const int dg = deg[node];
    float acc = u1[(long)node * H + lane];   // self
    for (int j0 = 0; j0 < dg; j0 += 64) {
        const int nj = min(64, dg - j0);
        int sv = 0;
        if (lane < nj) sv = src_sorted[rs + j0 + lane];
        int j = 0;
        for (; j + 4 <= nj; j += 4) {
            const int s0 = __shfl(sv, j, 64);
            const int s1 = __shfl(sv, j + 1, 64);
            const int s2 = __shfl(sv, j + 2, 64);
            const int s3 = __shfl(sv, j + 3, 64);
            const float v0 = u1[(long)s0 * H + lane];
            const float v1 = u1[(long)s1 * H + lane];
            const float v2 = u1[(long)s2 * H + lane];
            const float v3 = u1[(long)s3 * H + lane];
            acc += v0; acc += v1; acc += v2; acc += v3;
        }
        for (; j < nj; ++j) {
            const int s = __shfl(sv, j, 64);
            acc += u1[(long)s * H + lane];
        }
    }
    const float di = dinv[node];
    const float h = fmaxf(di * acc + b1[lane], 0.f);
    #pragma unroll
    for (int j = 0; j < 7; ++j) {
        float s = h * w2[lane * 7 + j];
        #pragma unroll
        for (int m = 1; m < 64; m <<= 1) s += __shfl_xor(s, m, 64);
        if (lane == j) u2[node * 8 + j] = di * s;
    }
}

// ---------------- layer2: CSR gather-aggregate + final transform ----------------
__global__ __launch_bounds__(256)
void layer2_csr_k(const int* __restrict__ row_start, const int* __restrict__ deg,
                  const int* __restrict__ src_sorted, const float* __restrict__ u2,
                  const float* __restrict__ dinv, const float* __restrict__ b2,
                  float* __restrict__ out) {
    const int t = threadIdx.x;
    const int c = t & 7;
    const int node = blockIdx.x * 32 + (t >> 3);
    if (node >= NN) return;
    const int rs = row_start[node];
    const int dg = deg[node];
    float acc = (c < 7) ? u2[node * 8 + c] : 0.f;   // self
    int j = 0;
    for (; j + 4 <= dg; j += 4) {
        const int s0 = src_sorted[rs + j];
        const int s1 = src_sorted[rs + j + 1];
        const int s2 = src_sorted[rs + j + 2];
        const int s3 = src_sorted[rs + j + 3];
        if (c < 7) {
            acc += u2[s0 * 8 + c];
            acc += u2[s1 * 8 + c];
            acc += u2[s2 * 8 + c];
            acc += u2[s3 * 8 + c];
        }
    }
    for (; j < dg; ++j) {
        const int s = src_sorted[rs + j];
        if (c < 7) acc += u2[s * 8 + c];
    }
    if (c < 7) out[node * 7 + c] = dinv[node] * acc + b2[c];
}

extern "C" void kernel_launch(void* const* d_in, const int* in_sizes, int n_in,
                              void* d_out, int out_size, void* d_ws, size_t ws_size,
                              hipStream_t stream) {
    const float* x      = (const float*)d_in[0];
    const float* txt    = (const float*)d_in[1];
    const int*   ei     = (const int*)d_in[2];
    const float* w_feat = (const float*)d_in[3];
    const float* b_feat = (const float*)d_in[4];
    const float* w_text = (const float*)d_in[5];
    const float* b_text = (const float*)d_in[6];
    const float* w1     = (const float*)d_in[7];
    const float* b1     = (const float*)d_in[8];
    const float* w2     = (const float*)d_in[9];
    const float* b2     = (const float*)d_in[10];
    float* out = (float*)d_out;

    char* p = (char*)d_ws;
    auto alloc = [&](size_t bytes) {
        char* r = p;
        p += (bytes + 255) & ~(size_t)255;
        return r;
    };
    ushort_t* WfxT = (ushort_t*)alloc((size_t)H * KP * 2);
    ushort_t* WtxT = (ushort_t*)alloc((size_t)H * KP * 2);
    float* bpre = (float*)alloc(H * 4);
    int*   deg  = (int*)alloc((size_t)NN * 4);
    float* dinv = (float*)alloc((size_t)NN * 4);
    int*   row_start = (int*)alloc((size_t)NN * 4);
    int*   cursor    = (int*)alloc((size_t)NN * 4);
    int*   partial   = (int*)alloc((size_t)SCAN_BLOCKS * 4);
    int*   psum      = (int*)alloc((size_t)SCAN_BLOCKS * 4);
    int*   src_sorted = (int*)alloc((size_t)NE * 4);
    float* u1   = (float*)alloc((size_t)NN * H * 4);
    float* u2   = (float*)alloc((size_t)NN * 8 * 4);

    hipMemsetAsync(deg, 0, (size_t)NN * 4, stream);

    const int fuse_tot = 2 * H * KP + H;
    fuse_k<<<(fuse_tot + 255) / 256, 256, 0, stream>>>(w_feat, b_feat, w_text, b_text, w1,
                                                       WfxT, WtxT, bpre);
    deg_k<<<(NE + 255) / 256, 256, 0, stream>>>(ei, deg);
    dinv_k<<<(NN + 255) / 256, 256, 0, stream>>>(deg, dinv);
    partial_k<<<SCAN_BLOCKS, 256, 0, stream>>>(deg, partial);
    scanp_k<<<1, 128, 0, stream>>>(partial, psum);
    offsets_k<<<SCAN_BLOCKS, 256, 0, stream>>>(deg, psum, row_start, cursor);
    sort_k<<<(NE + 255) / 256, 256, 0, stream>>>(ei, cursor, src_sorted);
    gemm1_mfma<<<(NN + BM - 1) / BM, 256, 0, stream>>>(x, txt, WfxT, WtxT, bpre, dinv, u1);
    layer1_csr_k<<<(NN + 3) / 4, 256, 0, stream>>>(row_start, deg, src_sorted, u1,
                                                   dinv, b1, w2, u2);
    layer2_csr_k<<<(NN + 31) / 32, 256, 0, stream>>>(row_start, deg, src_sorted, u2,
                                                     dinv, b2, out);
}